// Round 1
// baseline (168.256 us; speedup 1.0000x reference)
//
#include <hip/hip_runtime.h>

typedef short s16x8 __attribute__((ext_vector_type(8)));
typedef float f32x4 __attribute__((ext_vector_type(4)));

__device__ __forceinline__ unsigned short bf16r(float f) {
  unsigned int u = __float_as_uint(f);
  u += 0x7fffu + ((u >> 16) & 1u);
  return (unsigned short)(u >> 16);
}

// ---------------- Kernel 1: adaptive max pool 50x50 -> 5x5 ----------------
// grid: 16*8*64 = 8192 blocks (one per (b,l,c) plane), 256 threads
__global__ __launch_bounds__(256) void pool_kernel(const float* __restrict__ x,
                                                   float* __restrict__ pooled) {
  const int blk = blockIdx.x;  // ((b*8+l)*64+c)
  const float* plane = x + (size_t)blk * 2500;
  __shared__ float pmax[250];
  const int t = threadIdx.x;
  if (t < 250) {
    int r = t / 5, cc = t % 5;
    const float* row = plane + r * 50 + cc * 10;
    float m = row[0];
#pragma unroll
    for (int j = 1; j < 10; ++j) m = fmaxf(m, row[j]);
    pmax[r * 5 + cc] = m;
  }
  __syncthreads();
  if (t < 25) {
    int pr = t / 5, cc = t % 5;
    float m = pmax[(pr * 10) * 5 + cc];
#pragma unroll
    for (int rr = 1; rr < 10; ++rr) m = fmaxf(m, pmax[(pr * 10 + rr) * 5 + cc]);
    pooled[(size_t)blk * 25 + t] = m;  // t == pr*5+cc
  }
}

// ------------- Kernel 2: repack weight into bf16 MFMA A-fragment order ----
// wt2 flat index: ((((tap*2+ik)*4+mf)*64)+lane)*8 + j
// value = weight[o][i][tap], o = mf*16+(lane&15), i = ik*32+8*(lane>>4)+j
__global__ __launch_bounds__(256) void wt_kernel(const float* __restrict__ w,
                                                 unsigned short* __restrict__ wt2) {
  int idx = blockIdx.x * 256 + threadIdx.x;
  if (idx >= 9 * 2 * 4 * 64 * 8) return;  // 36864
  int j = idx & 7;
  int lane = (idx >> 3) & 63;
  int mf = (idx >> 9) & 3;
  int ik = (idx >> 11) & 1;
  int tap = idx >> 12;
  int o = mf * 16 + (lane & 15);
  int i = ik * 32 + 8 * (lane >> 4) + j;
  wt2[idx] = bf16r(w[((o * 64) + i) * 9 + tap]);
}

// ------------- Kernel 3: small 3x3 convs on the 5x5 pooled maps -----------
// conv with 64 output channels: thread = (co = t&63, quadrant qd = t>>6 of ci)
__device__ __forceinline__ void conv64(const float* pool_s, const float* __restrict__ wgt,
                                       const float* __restrict__ bias, float* red,
                                       float* __restrict__ outg, int tid) {
  int co = tid & 63, qd = tid >> 6;
  float acc[25];
#pragma unroll
  for (int n = 0; n < 25; ++n) acc[n] = 0.f;
  for (int ci = qd * 16; ci < qd * 16 + 16; ++ci) {
    float in[25];
#pragma unroll
    for (int n = 0; n < 25; ++n) in[n] = pool_s[ci * 25 + n];
    float w9[9];
#pragma unroll
    for (int tp = 0; tp < 9; ++tp) w9[tp] = wgt[(co * 64 + ci) * 9 + tp];
#pragma unroll
    for (int n = 0; n < 25; ++n) {
      int y = n / 5, xx = n % 5;
#pragma unroll
      for (int dy = 0; dy < 3; ++dy) {
        int yy = y + dy - 1;
        if (yy < 0 || yy > 4) continue;
#pragma unroll
        for (int dx = 0; dx < 3; ++dx) {
          int xc = xx + dx - 1;
          if (xc < 0 || xc > 4) continue;
          acc[n] += in[yy * 5 + xc] * w9[dy * 3 + dx];
        }
      }
    }
  }
#pragma unroll
  for (int n = 0; n < 25; ++n) red[(qd * 64 + co) * 25 + n] = acc[n];
  __syncthreads();
  for (int idx = tid; idx < 1600; idx += 256) {
    float s = red[idx] + red[1600 + idx] + red[3200 + idx] + red[4800 + idx];
    outg[idx] = s + bias[idx / 25];
  }
  __syncthreads();
}

// conv with 4 output channels: thread = (co = t&3, ci = t>>2)
__device__ __forceinline__ void conv4(const float* pool_s, const float* __restrict__ wgt,
                                      const float* __restrict__ bias, float* red,
                                      float* __restrict__ outg, int tid) {
  int co = tid & 3, ci = tid >> 2;
  float acc[25];
#pragma unroll
  for (int n = 0; n < 25; ++n) acc[n] = 0.f;
  float in[25];
#pragma unroll
  for (int n = 0; n < 25; ++n) in[n] = pool_s[ci * 25 + n];
  float w9[9];
#pragma unroll
  for (int tp = 0; tp < 9; ++tp) w9[tp] = wgt[(co * 64 + ci) * 9 + tp];
#pragma unroll
  for (int n = 0; n < 25; ++n) {
    int y = n / 5, xx = n % 5;
#pragma unroll
    for (int dy = 0; dy < 3; ++dy) {
      int yy = y + dy - 1;
      if (yy < 0 || yy > 4) continue;
#pragma unroll
      for (int dx = 0; dx < 3; ++dx) {
        int xc = xx + dx - 1;
        if (xc < 0 || xc > 4) continue;
        acc[n] += in[yy * 5 + xc] * w9[dy * 3 + dx];
      }
    }
  }
#pragma unroll
  for (int n = 0; n < 25; ++n) red[(ci * 4 + co) * 25 + n] = acc[n];
  __syncthreads();
  if (tid < 100) {
    int co2 = tid / 25, n = tid % 25;
    float s = 0.f;
    for (int c = 0; c < 64; ++c) s += red[(c * 4 + co2) * 25 + n];
    outg[co2 * 25 + n] = s + bias[co2];
  }
  __syncthreads();
}

// grid: 128 blocks (b*8+l), 256 threads
__global__ __launch_bounds__(256) void convB_kernel(
    const float* __restrict__ pooled, const float* __restrict__ vw,
    const float* __restrict__ vb, const float* __restrict__ kw,
    const float* __restrict__ kb, const float* __restrict__ iw,
    const float* __restrict__ ib, float* __restrict__ vconv,
    float* __restrict__ kconv, float* __restrict__ prior0) {
  const int blk = blockIdx.x;
  __shared__ float pool_s[1600];
  __shared__ float red[6400];
  const int tid = threadIdx.x;
  for (int idx = tid; idx < 1600; idx += 256) pool_s[idx] = pooled[blk * 1600 + idx];
  __syncthreads();
  conv64(pool_s, vw, vb, red, vconv + blk * 1600, tid);
  conv4(pool_s, kw, kb, red, kconv + blk * 100, tid);
  if ((blk & 7) == 0) conv64(pool_s, iw, ib, red, prior0 + (blk >> 3) * 1600, tid);
}

// ------------- Kernel 4: sequential attention scan + scale/fb -------------
// grid: 16 blocks (one per batch), 256 threads
__global__ __launch_bounds__(256) void scan_kernel(
    const float* __restrict__ vconv, const float* __restrict__ kconv,
    const float* __restrict__ prior0, const float* __restrict__ qw,
    const float* __restrict__ qb, const float* __restrict__ tconvw,
    const float* __restrict__ tconvb, const float* __restrict__ fcw,
    const float* __restrict__ fcb, const float* __restrict__ bias,
    float* __restrict__ scale_g, float* __restrict__ fb_g) {
  const int b = blockIdx.x;
  const int tid = threadIdx.x;
  __shared__ float p_s[1600], v_s[1600], kk_s[100], q_s[100];
  __shared__ float qw_s[2304];
  __shared__ float tcw_s[64 * 65];  // padded stride 65 to break bank conflicts
  __shared__ float attn_s[625];
  __shared__ float red[6400];
  __shared__ float avg_s[64];

  for (int idx = tid; idx < 1600; idx += 256) p_s[idx] = prior0[b * 1600 + idx];
  for (int idx = tid; idx < 2304; idx += 256) qw_s[idx] = qw[idx];
  for (int idx = tid; idx < 4096; idx += 256) tcw_s[(idx / 64) * 65 + (idx % 64)] = tconvw[idx];
  __syncthreads();

  const int qco = tid & 3, qci = tid >> 2;
  float qwr[9];
#pragma unroll
  for (int tp = 0; tp < 9; ++tp) qwr[tp] = qw_s[(qco * 64 + qci) * 9 + tp];

  for (int l = 0; l < 8; ++l) {
    const int bl = b * 8 + l;
    for (int idx = tid; idx < 1600; idx += 256) v_s[idx] = vconv[bl * 1600 + idx];
    if (tid < 100) kk_s[tid] = kconv[bl * 100 + tid];
    __syncthreads();

    // q conv partial: thread = (qco, qci), full 225-FMA tap block on p_s[qci]
    {
      float in[25];
#pragma unroll
      for (int n = 0; n < 25; ++n) in[n] = p_s[qci * 25 + n];
      float acc[25];
#pragma unroll
      for (int n = 0; n < 25; ++n) acc[n] = 0.f;
#pragma unroll
      for (int n = 0; n < 25; ++n) {
        int y = n / 5, xx = n % 5;
#pragma unroll
        for (int dy = 0; dy < 3; ++dy) {
          int yy = y + dy - 1;
          if (yy < 0 || yy > 4) continue;
#pragma unroll
          for (int dx = 0; dx < 3; ++dx) {
            int xc = xx + dx - 1;
            if (xc < 0 || xc > 4) continue;
            acc[n] += in[yy * 5 + xc] * qwr[dy * 3 + dx];
          }
        }
      }
#pragma unroll
      for (int n = 0; n < 25; ++n) red[(qci * 4 + qco) * 25 + n] = acc[n];
    }
    __syncthreads();
    if (tid < 100) {  // reduce 64 ci partials
      int co = tid / 25, n = tid % 25;
      float s = qb[co];
      for (int c = 0; c < 64; ++c) s += red[(c * 4 + co) * 25 + n];
      q_s[co * 25 + n] = s;
    }
    __syncthreads();
    // logits[n][m] = sum_c q[c][n]*kk[c][m]
    for (int idx = tid; idx < 625; idx += 256) {
      int n = idx / 25, m = idx % 25;
      float s = 0.f;
#pragma unroll
      for (int c = 0; c < 4; ++c) s += q_s[c * 25 + n] * kk_s[c * 25 + m];
      attn_s[idx] = s;
    }
    __syncthreads();
    // softmax over m (rows)
    if (tid < 25) {
      float* row = attn_s + tid * 25;
      float mx = row[0];
#pragma unroll
      for (int m = 1; m < 25; ++m) mx = fmaxf(mx, row[m]);
      float sm = 0.f;
#pragma unroll
      for (int m = 0; m < 25; ++m) {
        float e = __expf(row[m] - mx);
        row[m] = e;
        sm += e;
      }
      float inv = 1.0f / sm;
#pragma unroll
      for (int m = 0; m < 25; ++m) row[m] *= inv;
    }
    __syncthreads();
    // pv: p_new[c][n] = sum_m v[c][m]*attn[n][m]  (writes p_s in place)
    if (tid < 200) {
      int n = tid % 25, cc = tid / 25;  // cc in [0,8)
      float ar[25];
#pragma unroll
      for (int m = 0; m < 25; ++m) ar[m] = attn_s[n * 25 + m];
#pragma unroll
      for (int cj = 0; cj < 8; ++cj) {
        int c = cc * 8 + cj;
        float s = 0.f;
#pragma unroll
        for (int m = 0; m < 25; ++m) s += v_s[c * 25 + m] * ar[m];
        p_s[c * 25 + n] = s;
      }
    }
    __syncthreads();
    if (tid < 64) {
      float s = 0.f;
#pragma unroll
      for (int n = 0; n < 25; ++n) s += p_s[tid * 25 + n];
      avg_s[tid] = s * 0.04f;
    }
    __syncthreads();
    if (tid < 64) {
      int o = tid;
      float cal = tconvb[o];
      for (int c = 0; c < 64; ++c) cal += tcw_s[o * 65 + c] * avg_s[c];
      scale_g[bl * 64 + o] = 1.0f + cal;
      float part = fcw[o] * avg_s[o];
#pragma unroll
      for (int off = 32; off; off >>= 1) part += __shfl_down(part, off);
      float fc = __shfl(part, 0) + fcb[0];
      fb_g[bl * 64 + o] = bias[o] * (1.0f + fc);
    }
    __syncthreads();
  }
}

// ------------- Kernel 5: main conv as shared-weight MFMA GEMM -------------
// out[g,o,y,x] = sum_{i,dy,dx} (x[g,i,y+dy-1,x+dx-1]*scale[g,i]) * W[o,i,dy,dx] + fb[g,o]
// block: one g, 4 output rows; LDS tile [6 rows][66 cols][64 i] bf16, i-chunk XOR swizzle
__global__ __launch_bounds__(256) void conv_main(
    const float* __restrict__ x, const unsigned short* __restrict__ wt2,
    const float* __restrict__ scale_g, const float* __restrict__ fb_g,
    float* __restrict__ out) {
  const int g = blockIdx.x & 127;     // same-g bands land on the same XCD
  const int band = blockIdx.x >> 7;   // 0..12
  const int y0 = band * 4;
  const int tid = threadIdx.x;
  __shared__ unsigned short in_s[6 * 66 * 64];
  __shared__ float scale_s[64], fb_s[64];
  if (tid < 64) {
    scale_s[tid] = scale_g[g * 64 + tid];
    fb_s[tid] = fb_g[g * 64 + tid];
  }
  __syncthreads();

  const float* xg = x + (size_t)g * 160000;
  // stage: task = ((r*8+chunk)*66)+c ; 8 consecutive i per task -> b128 write
  for (int task = tid; task < 3168; task += 256) {
    int c = task % 66;
    int rc = task / 66;
    int r = rc >> 3;
    int chunk = rc & 7;
    int y = y0 - 1 + r;
    int xi = c - 1;
    unsigned int p0 = 0, p1 = 0, p2 = 0, p3 = 0;
    if (y >= 0 && y < 50 && xi >= 0 && xi < 50) {
      const float* px = xg + chunk * 8 * 2500 + y * 50 + xi;
      float f0 = px[0] * scale_s[chunk * 8 + 0];
      float f1 = px[2500] * scale_s[chunk * 8 + 1];
      float f2 = px[5000] * scale_s[chunk * 8 + 2];
      float f3 = px[7500] * scale_s[chunk * 8 + 3];
      float f4 = px[10000] * scale_s[chunk * 8 + 4];
      float f5 = px[12500] * scale_s[chunk * 8 + 5];
      float f6 = px[15000] * scale_s[chunk * 8 + 6];
      float f7 = px[17500] * scale_s[chunk * 8 + 7];
      p0 = (unsigned)bf16r(f0) | ((unsigned)bf16r(f1) << 16);
      p1 = (unsigned)bf16r(f2) | ((unsigned)bf16r(f3) << 16);
      p2 = (unsigned)bf16r(f4) | ((unsigned)bf16r(f5) << 16);
      p3 = (unsigned)bf16r(f6) | ((unsigned)bf16r(f7) << 16);
    }
    int chS = chunk ^ (c & 7);
    uint4* dst = (uint4*)&in_s[((r * 66 + c) << 6) + (chS << 3)];
    uint4 u4;
    u4.x = p0; u4.y = p1; u4.z = p2; u4.w = p3;
    *dst = u4;
  }
  __syncthreads();

  const int wave = tid >> 6, lane = tid & 63;
  const int l15 = lane & 15, l4 = lane >> 4;
  const int yrow = y0 + wave;
  if (yrow < 50) {
    f32x4 acc[4][4];
    f32x4 z = {0.f, 0.f, 0.f, 0.f};
#pragma unroll
    for (int mf = 0; mf < 4; ++mf)
#pragma unroll
      for (int nf = 0; nf < 4; ++nf) acc[mf][nf] = z;

#pragma unroll
    for (int dy = 0; dy < 3; ++dy) {
      const int rr = wave + dy;
#pragma unroll
      for (int dx = 0; dx < 3; ++dx) {
        const int tap = dy * 3 + dx;
#pragma unroll
        for (int ik = 0; ik < 2; ++ik) {
          s16x8 a[4], bfr[4];
#pragma unroll
          for (int mf = 0; mf < 4; ++mf)
            a[mf] = *reinterpret_cast<const s16x8*>(
                wt2 + ((((tap * 2 + ik) * 4 + mf) * 64 + lane) << 3));
#pragma unroll
          for (int nf = 0; nf < 4; ++nf) {
            int cc = nf * 16 + l15 + dx;
            int chS = (ik * 4 + l4) ^ (cc & 7);
            bfr[nf] = *reinterpret_cast<const s16x8*>(
                &in_s[((rr * 66 + cc) << 6) + (chS << 3)]);
          }
#pragma unroll
          for (int mf = 0; mf < 4; ++mf)
#pragma unroll
            for (int nf = 0; nf < 4; ++nf)
              acc[mf][nf] = __builtin_amdgcn_mfma_f32_16x16x32_bf16(
                  a[mf], bfr[nf], acc[mf][nf], 0, 0, 0);
        }
      }
    }
    // D layout: col = lane&15 (x), row = (lane>>4)*4 + r (o)
    float* og = out + (size_t)g * 64 * 2500 + yrow * 50;
#pragma unroll
    for (int mf = 0; mf < 4; ++mf) {
#pragma unroll
      for (int r = 0; r < 4; ++r) {
        int o = mf * 16 + l4 * 4 + r;
        float fbv = fb_s[o];
#pragma unroll
        for (int nf = 0; nf < 4; ++nf) {
          int xx = nf * 16 + l15;
          if (xx < 50) og[(size_t)o * 2500 + xx] = acc[mf][nf][r] + fbv;
        }
      }
    }
  }
}

// --------------------------------- launch ---------------------------------
extern "C" void kernel_launch(void* const* d_in, const int* in_sizes, int n_in,
                              void* d_out, int out_size, void* d_ws, size_t ws_size,
                              hipStream_t stream) {
  const float* x       = (const float*)d_in[0];
  const float* weight  = (const float*)d_in[1];
  const float* bias    = (const float*)d_in[2];
  const float* init_w  = (const float*)d_in[3];
  const float* init_b  = (const float*)d_in[4];
  const float* q_w     = (const float*)d_in[5];
  const float* q_b     = (const float*)d_in[6];
  const float* k_w     = (const float*)d_in[7];
  const float* k_b     = (const float*)d_in[8];
  const float* v_w     = (const float*)d_in[9];
  const float* v_b     = (const float*)d_in[10];
  const float* tconv_w = (const float*)d_in[11];
  const float* tconv_b = (const float*)d_in[12];
  const float* fc_w    = (const float*)d_in[13];
  const float* fc_b    = (const float*)d_in[14];
  float* out = (float*)d_out;

  float* ws = (float*)d_ws;
  float* pooled = ws;                  // 204800
  float* vconv  = ws + 204800;         // 204800
  float* kconv  = ws + 409600;         // 12800
  float* prior0 = ws + 422400;         // 25600
  float* scaleg = ws + 448000;         // 8192
  float* fbg    = ws + 456192;         // 8192
  unsigned short* wt2 = (unsigned short*)(ws + 464384);  // 36864 ushort

  pool_kernel<<<8192, 256, 0, stream>>>(x, pooled);
  wt_kernel<<<144, 256, 0, stream>>>(weight, wt2);
  convB_kernel<<<128, 256, 0, stream>>>(pooled, v_w, v_b, k_w, k_b, init_w, init_b,
                                        vconv, kconv, prior0);
  scan_kernel<<<16, 256, 0, stream>>>(vconv, kconv, prior0, q_w, q_b, tconv_w,
                                      tconv_b, fc_w, fc_b, bias, scaleg, fbg);
  conv_main<<<13 * 128, 256, 0, stream>>>(x, wt2, scaleg, fbg, out);
}